// Round 1
// baseline (2371.808 us; speedup 1.0000x reference)
//
#include <hip/hip_runtime.h>
#include <cstdint>

#pragma clang fp contract(off)

#define BS   128
#define NQ   900
#define NC   91
#define NQC  (NQ * NC)   // 81900
#define PRE  10000
#define POST 100
#define CAP  16384
#define HALFN 8192

// monotone ascending mapping float -> uint32 (no NaNs in data)
__device__ __forceinline__ uint32_t fkey(float f) {
    uint32_t b = __float_as_uint(f);
    return (b & 0x80000000u) ? ~b : (b | 0x80000000u);
}

// ---------------- Kernel A: per-image threshold via 4-level byte radix refinement ----------------
__global__ void k_thresh(const float* __restrict__ logits, uint32_t* __restrict__ T,
                         uint32_t* __restrict__ cnt) {
    int img = blockIdx.x;
    const float* lg = logits + (size_t)img * NQC;
    __shared__ uint32_t hist[256];
    __shared__ uint32_t sPrefix;
    __shared__ int sK;
    if (threadIdx.x == 0) { sPrefix = 0u; sK = PRE; cnt[img] = 0u; }
    __syncthreads();
    for (int level = 3; level >= 0; --level) {
        for (int i = threadIdx.x; i < 256; i += blockDim.x) hist[i] = 0u;
        __syncthreads();
        uint32_t pref = sPrefix;
        int shift = level * 8;
        for (int i = threadIdx.x; i < NQC; i += blockDim.x) {
            uint32_t u = fkey(lg[i]);
            if ((((uint64_t)u) >> (shift + 8)) == (uint64_t)pref)
                atomicAdd(&hist[(u >> shift) & 0xFFu], 1u);
        }
        __syncthreads();
        if (threadIdx.x == 0) {
            int K = sK;
            uint32_t cum = 0u;
            for (int b = 255; b >= 0; --b) {
                uint32_t c = hist[b];
                if (cum + c >= (uint32_t)K) {
                    sK = K - (int)cum;
                    sPrefix = (pref << 8) | (uint32_t)b;
                    break;
                }
                cum += c;
            }
        }
        __syncthreads();
    }
    if (threadIdx.x == 0) T[img] = sPrefix;
}

// ---------------- Kernel B: compact all items with key >= T ----------------
__global__ void k_compact(const float* __restrict__ logits, const uint32_t* __restrict__ T,
                          uint32_t* __restrict__ cnt, unsigned long long* __restrict__ keys) {
    int img = blockIdx.y;
    int i = blockIdx.x * blockDim.x + threadIdx.x;
    if (i >= NQC) return;
    uint32_t u = fkey(logits[(size_t)img * NQC + i]);
    if (u >= T[img]) {
        uint32_t pos = atomicAdd(&cnt[img], 1u);
        if (pos < CAP)
            keys[(size_t)img * CAP + pos] =
                ((unsigned long long)u << 32) | (unsigned long long)(0xFFFFFFFFu - (uint32_t)i);
    }
}

// ---------------- Kernel C: per-image bitonic sort of two 8192 halves (descending) ----------------
__global__ void __launch_bounds__(1024) k_sort(unsigned long long* __restrict__ keys,
                                               const uint32_t* __restrict__ cnt) {
    int img = blockIdx.x;
    uint32_t n = cnt[img]; if (n > CAP) n = CAP;
    __shared__ unsigned long long sh[HALFN];   // 64 KB
    unsigned long long* base = keys + (size_t)img * CAP;
    for (int half = 0; half < 2; ++half) {
        for (int i = threadIdx.x; i < HALFN; i += blockDim.x) {
            int g = half * HALFN + i;
            sh[i] = (g < (int)n) ? base[g] : 0ull;
        }
        __syncthreads();
        for (int k = 2; k <= HALFN; k <<= 1) {
            for (int j = k >> 1; j > 0; j >>= 1) {
                for (int t = threadIdx.x; t < HALFN / 2; t += blockDim.x) {
                    int i = ((t & ~(j - 1)) << 1) | (t & (j - 1));
                    int ixj = i | j;
                    unsigned long long a = sh[i], b = sh[ixj];
                    bool sw = ((i & k) == 0) ? (a < b) : (a > b);
                    if (sw) { sh[i] = b; sh[ixj] = a; }
                }
                __syncthreads();
            }
        }
        for (int i = threadIdx.x; i < HALFN; i += blockDim.x)
            base[half * HALFN + i] = sh[i];
        __syncthreads();
    }
}

// ---------------- Kernel D: merge-rank scatter of the two sorted halves -> top[PRE] ----------------
__global__ void k_merge(const unsigned long long* __restrict__ keys,
                        unsigned long long* __restrict__ top) {
    int img = blockIdx.y;
    int e = blockIdx.x * blockDim.x + threadIdx.x;  // [0, CAP)
    const unsigned long long* base = keys + (size_t)img * CAP;
    unsigned long long x = base[e];
    if (x == 0ull) return;  // padding
    int half = e >> 13;
    int pos = e & (HALFN - 1);
    const unsigned long long* other = base + (half ? 0 : HALFN);
    int lo = 0, hi = HALFN;
    while (lo < hi) {
        int mid = (lo + hi) >> 1;
        if (other[mid] > x) lo = mid + 1; else hi = mid;
    }
    int rank = pos + lo;
    if (rank < PRE) top[(size_t)img * PRE + rank] = x;
}

// ---------------- Kernel E: greedy NMS per image ----------------
__global__ void __launch_bounds__(1024) k_nms(const unsigned long long* __restrict__ top,
                                              const float* __restrict__ pred_boxes,
                                              const float* __restrict__ target_sizes,
                                              float* __restrict__ out) {
    int img = blockIdx.x;
    __shared__ uint32_t fidx[PRE];
    __shared__ unsigned char act[PRE];
    __shared__ float red[16];
    __shared__ float sOffD;
    const float ih = target_sizes[img * 2 + 0];
    const float iw = target_sizes[img * 2 + 1];
    const float* pb = pred_boxes + (size_t)img * NQ * 4;

    float mx = -INFINITY;
    for (int r = threadIdx.x; r < PRE; r += blockDim.x) {
        unsigned long long key = top[(size_t)img * PRE + r];
        uint32_t f = 0xFFFFFFFFu - (uint32_t)key;
        fidx[r] = f;
        act[r] = 1;
        uint32_t q = f / NC;
        float cx = pb[q * 4 + 0], cy = pb[q * 4 + 1], w = pb[q * 4 + 2], h = pb[q * 4 + 3];
        float x1 = (cx - 0.5f * w) * iw;
        float y1 = (cy - 0.5f * h) * ih;
        float x2 = (cx + 0.5f * w) * iw;
        float y2 = (cy + 0.5f * h) * ih;
        mx = fmaxf(mx, fmaxf(fmaxf(x1, y1), fmaxf(x2, y2)));
    }
    for (int off = 32; off > 0; off >>= 1) mx = fmaxf(mx, __shfl_down(mx, off, 64));
    int wave = threadIdx.x >> 6;
    int lane = threadIdx.x & 63;
    if (lane == 0) red[wave] = mx;
    __syncthreads();
    if (threadIdx.x == 0) {
        float m = red[0];
        int nw = blockDim.x >> 6;
        for (int wv = 1; wv < nw; ++wv) m = fmaxf(m, red[wv]);
        sOffD = m + 1.0f;  // max_coord + 1
    }
    __syncthreads();
    const float offD = sOffD;

    int start = 0;
    for (int pick = 0; pick < POST; ++pick) {
        while (start < PRE && act[start] == 0) ++start;   // uniform across all threads
        int i = (start < PRE) ? start : 0;                // argmax over all -inf -> 0

        uint32_t fi = fidx[i];
        uint32_t qi = fi / NC;
        uint32_t ci = fi - qi * NC;
        float cx = pb[qi * 4 + 0], cy = pb[qi * 4 + 1], w = pb[qi * 4 + 2], h = pb[qi * 4 + 3];
        float bx1 = (cx - 0.5f * w) * iw;
        float by1 = (cy - 0.5f * h) * ih;
        float bx2 = (cx + 0.5f * w) * iw;
        float by2 = (cy + 0.5f * h) * ih;
        float oi = (float)ci * offD;
        float ox1 = bx1 + oi, oy1 = by1 + oi, ox2 = bx2 + oi, oy2 = by2 + oi;
        float areai = (ox2 - ox1) * (oy2 - oy1);

        if (threadIdx.x == 0) {
            unsigned long long key = top[(size_t)img * PRE + i];
            uint32_t u = (uint32_t)(key >> 32);
            uint32_t b = (u & 0x80000000u) ? (u & 0x7FFFFFFFu) : ~u;
            float logit = __uint_as_float(b);
            float score = 1.0f / (1.0f + expf(-logit));
            out[img * POST + pick] = score;
            out[BS * POST + img * POST + pick] = (float)ci;
            float* ob = out + 2 * BS * POST + ((size_t)img * POST + pick) * 4;
            ob[0] = bx1; ob[1] = by1; ob[2] = bx2; ob[3] = by2;
        }

        if (start < PRE) {
            for (int jj = start + (int)threadIdx.x; jj < PRE; jj += blockDim.x) {
                if (!act[jj]) continue;
                uint32_t fj = fidx[jj];
                uint32_t qj = fj / NC;
                uint32_t cj = fj - qj * NC;
                float jcx = pb[qj * 4 + 0], jcy = pb[qj * 4 + 1], jw = pb[qj * 4 + 2], jh = pb[qj * 4 + 3];
                float jx1 = (jcx - 0.5f * jw) * iw;
                float jy1 = (jcy - 0.5f * jh) * ih;
                float jx2 = (jcx + 0.5f * jw) * iw;
                float jy2 = (jcy + 0.5f * jh) * ih;
                float oj = (float)cj * offD;
                float jox1 = jx1 + oj, joy1 = jy1 + oj, jox2 = jx2 + oj, joy2 = jy2 + oj;
                float areaj = (jox2 - jox1) * (joy2 - joy1);
                float xx1 = fmaxf(ox1, jox1);
                float yy1 = fmaxf(oy1, joy1);
                float xx2 = fminf(ox2, jox2);
                float yy2 = fminf(oy2, joy2);
                float inter = fmaxf(xx2 - xx1, 0.0f) * fmaxf(yy2 - yy1, 0.0f);
                float uni = (areai + areaj) - inter;
                float iou = inter / fmaxf(uni, 1e-9f);
                if (!(iou <= 0.7f)) act[jj] = 0;   // active &= (iou <= thresh)
            }
        }
        __syncthreads();
    }
}

extern "C" void kernel_launch(void* const* d_in, const int* in_sizes, int n_in,
                              void* d_out, int out_size, void* d_ws, size_t ws_size,
                              hipStream_t stream) {
    const float* logits = (const float*)d_in[0];       // [128,900,91]
    const float* boxes  = (const float*)d_in[1];       // [128,900,4]
    const float* tsizes = (const float*)d_in[2];       // [128,2]
    float* out = (float*)d_out;                        // 76800 floats

    char* ws = (char*)d_ws;
    uint32_t* T   = (uint32_t*)(ws);                   // 128 * 4
    uint32_t* cnt = (uint32_t*)(ws + 512);             // 128 * 4
    unsigned long long* keys = (unsigned long long*)(ws + 1024);                 // 128*16384*8 = 16 MB
    unsigned long long* top  = (unsigned long long*)(ws + 1024 + (size_t)BS * CAP * 8); // 128*10000*8

    k_thresh<<<BS, 256, 0, stream>>>(logits, T, cnt);
    k_compact<<<dim3((NQC + 255) / 256, BS), 256, 0, stream>>>(logits, T, cnt, keys);
    k_sort<<<BS, 1024, 0, stream>>>(keys, cnt);
    k_merge<<<dim3(CAP / 256, BS), 256, 0, stream>>>(keys, top);
    k_nms<<<BS, 1024, 0, stream>>>(top, boxes, tsizes, out);
}

// Round 2
// 544.071 us; speedup vs baseline: 4.3594x; 4.3594x over previous
//
#include <hip/hip_runtime.h>
#include <cstdint>

#pragma clang fp contract(off)

#define BS   128
#define NQ   900
#define NC   91
#define NQC  (NQ * NC)   // 81900
#define PRE  10000
#define POST 100
#define CAP  16384
#define HALFN 8192
#define CNTS 16          // cnt stride in uint32 (64B apart, avoid same-line atomic contention)
#define TBITS 13
#define TBINS (1 << TBITS)        // 8192 bins over top 13 key bits
#define TSHIFT (32 - TBITS)       // 19
#define WPRE 320                  // ceil(PRE/32) words for active bitmask

// monotone ascending mapping float -> uint32 (no NaNs in data)
__device__ __forceinline__ uint32_t fkey(float f) {
    uint32_t b = __float_as_uint(f);
    return (b & 0x80000000u) ? ~b : (b | 0x80000000u);
}

// ---------------- Kernel A: per-image approximate threshold, single pass ----------------
// Finds largest bin P with suffix-count(key >= P<<TSHIFT) >= PRE. Since sort+merge
// extract the exact top-PRE from any M in [PRE, CAP], an approximate T suffices as
// long as M <= CAP. Fallback 8-bit refinement if the bin is pathologically fat.
__global__ void __launch_bounds__(1024) k_thresh(const float* __restrict__ logits,
                                                 uint32_t* __restrict__ T,
                                                 uint32_t* __restrict__ cnt) {
    int img = blockIdx.x;
    __shared__ uint32_t hist[TBINS];   // 32 KB
    __shared__ uint32_t part[1024];
    __shared__ uint32_t part2[32];
    __shared__ uint32_t sP, sTotal, sT;
    for (int i = threadIdx.x; i < TBINS; i += 1024) hist[i] = 0u;
    if (threadIdx.x == 0) cnt[img * CNTS] = 0u;
    __syncthreads();
    const float4* lg4 = (const float4*)(logits + (size_t)img * NQC);  // NQC%4==0, 16B aligned
    for (int i = threadIdx.x; i < NQC / 4; i += 1024) {
        float4 v = lg4[i];
        atomicAdd(&hist[fkey(v.x) >> TSHIFT], 1u);
        atomicAdd(&hist[fkey(v.y) >> TSHIFT], 1u);
        atomicAdd(&hist[fkey(v.z) >> TSHIFT], 1u);
        atomicAdd(&hist[fkey(v.w) >> TSHIFT], 1u);
    }
    __syncthreads();
    // hierarchical suffix scan: 1024 partials of 8 bins, 32 super-partials of 32
    {
        uint32_t s = 0;
        int base = threadIdx.x * (TBINS / 1024);
        for (int j = 0; j < TBINS / 1024; ++j) s += hist[base + j];
        part[threadIdx.x] = s;
    }
    __syncthreads();
    if (threadIdx.x < 32) {
        uint32_t s2 = 0;
        for (int j = 0; j < 32; ++j) s2 += part[threadIdx.x * 32 + j];
        part2[threadIdx.x] = s2;
    }
    __syncthreads();
    if (threadIdx.x == 0) {
        uint32_t cum = 0;
        int w = 31;
        for (; w > 0; --w) { if (cum + part2[w] >= PRE) break; cum += part2[w]; }
        int t = w * 32 + 31;
        for (; t > w * 32; --t) { if (cum + part[t] >= PRE) break; cum += part[t]; }
        int b = t * (TBINS / 1024) + (TBINS / 1024 - 1);
        for (; b > t * (TBINS / 1024); --b) { if (cum + hist[b] >= PRE) break; cum += hist[b]; }
        sP = (uint32_t)b;
        sTotal = cum + hist[b];
        sT = ((uint32_t)b) << TSHIFT;
    }
    __syncthreads();
    if (sTotal > CAP) {   // fallback: refine 8 more bits within bin sP (block-uniform branch)
        uint32_t P = sP;
        for (int i = threadIdx.x; i < 256; i += 1024) part[i] = 0u;   // reuse part as hist2
        __syncthreads();
        for (int i = threadIdx.x; i < NQC / 4; i += 1024) {
            float4 v = lg4[i];
            uint32_t u;
            u = fkey(v.x); if ((u >> TSHIFT) == P) atomicAdd(&part[(u >> (TSHIFT - 8)) & 0xFFu], 1u);
            u = fkey(v.y); if ((u >> TSHIFT) == P) atomicAdd(&part[(u >> (TSHIFT - 8)) & 0xFFu], 1u);
            u = fkey(v.z); if ((u >> TSHIFT) == P) atomicAdd(&part[(u >> (TSHIFT - 8)) & 0xFFu], 1u);
            u = fkey(v.w); if ((u >> TSHIFT) == P) atomicAdd(&part[(u >> (TSHIFT - 8)) & 0xFFu], 1u);
        }
        __syncthreads();
        if (threadIdx.x == 0) {
            uint32_t countAbove = sTotal - hist[P];         // count(key >= (P+1)<<TSHIFT), < PRE
            uint32_t K = PRE - countAbove;
            uint32_t cum = 0; int x = 255;
            for (; x > 0; --x) { if (cum + part[x] >= K) break; cum += part[x]; }
            sT = (P << TSHIFT) | (((uint32_t)x) << (TSHIFT - 8));
        }
        __syncthreads();
    }
    if (threadIdx.x == 0) T[img] = sT;
}

// ---------------- Kernel B: compact items with key >= T (wave+block aggregated atomics) ----------------
__global__ void k_compact(const float* __restrict__ logits, const uint32_t* __restrict__ T,
                          uint32_t* __restrict__ cnt, unsigned long long* __restrict__ keys) {
    __shared__ uint32_t sTot, sBase;
    int img = blockIdx.y;
    int i = blockIdx.x * blockDim.x + threadIdx.x;
    if (threadIdx.x == 0) sTot = 0u;
    __syncthreads();
    uint32_t u = 0u;
    bool pass = false;
    if (i < NQC) {
        u = fkey(logits[(size_t)img * NQC + i]);
        pass = (u >= T[img]);
    }
    unsigned long long mask = __ballot(pass);
    int lane = threadIdx.x & 63;
    uint32_t below = (uint32_t)__popcll(mask & ((1ull << lane) - 1ull));
    uint32_t wtot = (uint32_t)__popcll(mask);
    uint32_t wbase = 0u;
    if (lane == 0 && wtot) wbase = atomicAdd(&sTot, wtot);
    wbase = __shfl(wbase, 0, 64);
    __syncthreads();
    if (threadIdx.x == 0 && sTot) sBase = atomicAdd(&cnt[img * CNTS], sTot);
    __syncthreads();
    if (pass) {
        uint32_t pos = sBase + wbase + below;
        if (pos < CAP)
            keys[(size_t)img * CAP + pos] =
                ((unsigned long long)u << 32) | (unsigned long long)(0xFFFFFFFFu - (uint32_t)i);
    }
}

// ---------------- Kernel C: per-image bitonic sort of two 8192 halves (descending) ----------------
__global__ void __launch_bounds__(1024) k_sort(unsigned long long* __restrict__ keys,
                                               const uint32_t* __restrict__ cnt) {
    int img = blockIdx.x;
    uint32_t n = cnt[img * CNTS]; if (n > CAP) n = CAP;
    __shared__ unsigned long long sh[HALFN];   // 64 KB
    unsigned long long* base = keys + (size_t)img * CAP;
    for (int half = 0; half < 2; ++half) {
        for (int i = threadIdx.x; i < HALFN; i += blockDim.x) {
            int g = half * HALFN + i;
            sh[i] = (g < (int)n) ? base[g] : 0ull;
        }
        __syncthreads();
        for (int k = 2; k <= HALFN; k <<= 1) {
            for (int j = k >> 1; j > 0; j >>= 1) {
                for (int t = threadIdx.x; t < HALFN / 2; t += blockDim.x) {
                    int i = ((t & ~(j - 1)) << 1) | (t & (j - 1));
                    int ixj = i | j;
                    unsigned long long a = sh[i], b = sh[ixj];
                    bool sw = ((i & k) == 0) ? (a < b) : (a > b);
                    if (sw) { sh[i] = b; sh[ixj] = a; }
                }
                __syncthreads();
            }
        }
        for (int i = threadIdx.x; i < HALFN; i += blockDim.x)
            base[half * HALFN + i] = sh[i];
        __syncthreads();
    }
}

// ---------------- Kernel D: merge-rank scatter of the two sorted halves -> top[PRE] ----------------
__global__ void k_merge(const unsigned long long* __restrict__ keys,
                        unsigned long long* __restrict__ top) {
    int img = blockIdx.y;
    int e = blockIdx.x * blockDim.x + threadIdx.x;  // [0, CAP)
    const unsigned long long* base = keys + (size_t)img * CAP;
    unsigned long long x = base[e];
    if (x == 0ull) return;  // padding
    int half = e >> 13;
    int pos = e & (HALFN - 1);
    const unsigned long long* other = base + (half ? 0 : HALFN);
    int lo = 0, hi = HALFN;
    while (lo < hi) {
        int mid = (lo + hi) >> 1;
        if (other[mid] > x) lo = mid + 1; else hi = mid;
    }
    int rank = pos + lo;
    if (rank < PRE) top[(size_t)img * PRE + rank] = x;
}

// ---------------- Kernel E: greedy NMS, boxes register-resident, bitmask active set ----------------
#define SLOTS 10   // 1024 threads x 10 slots covers PRE=10000
__global__ void __launch_bounds__(1024) k_nms(const unsigned long long* __restrict__ top,
                                              const float* __restrict__ pred_boxes,
                                              const float* __restrict__ target_sizes,
                                              float* __restrict__ out) {
    int img = blockIdx.x;
    __shared__ uint32_t fidx[PRE];     // 40 KB
    __shared__ uint32_t actw[WPRE];    // active bitmask, bit r = actw[r>>5] & (1<<(r&31))
    __shared__ float red[16];
    __shared__ float sOffD;
    const int tid = threadIdx.x;
    const float ih = target_sizes[img * 2 + 0];
    const float iw = target_sizes[img * 2 + 1];
    const float* pb = pred_boxes + (size_t)img * NQ * 4;

    // Phase 1: load keys, compute raw scaled boxes into registers, find max coord
    float bx1[SLOTS], by1[SLOTS], bx2[SLOTS], by2[SLOTS];
    int cls[SLOTS];
    float mx = -INFINITY;
    #pragma unroll
    for (int k = 0; k < SLOTS; ++k) {
        int r = tid + k * 1024;
        bool v = (r < PRE);
        uint32_t f = 0u;
        if (v) {
            unsigned long long key = top[(size_t)img * PRE + r];
            f = ~(uint32_t)key;
            fidx[r] = f;
        }
        uint32_t q = v ? (f / NC) : 0u;
        cls[k] = (int)(f - q * NC);
        float cx = pb[q * 4 + 0], cy = pb[q * 4 + 1], w = pb[q * 4 + 2], h = pb[q * 4 + 3];
        float x1 = (cx - 0.5f * w) * iw;
        float y1 = (cy - 0.5f * h) * ih;
        float x2 = (cx + 0.5f * w) * iw;
        float y2 = (cy + 0.5f * h) * ih;
        bx1[k] = x1; by1[k] = y1; bx2[k] = x2; by2[k] = y2;
        if (v) mx = fmaxf(mx, fmaxf(fmaxf(x1, y1), fmaxf(x2, y2)));
    }
    for (int wI = tid; wI < WPRE; wI += 1024) {
        int base = wI * 32;
        uint32_t m = 0xFFFFFFFFu;
        if (base + 32 > PRE) m = (base >= PRE) ? 0u : (0xFFFFFFFFu >> (base + 32 - PRE));
        actw[wI] = m;
    }
    for (int off = 32; off > 0; off >>= 1) mx = fmaxf(mx, __shfl_down(mx, off, 64));
    if ((tid & 63) == 0) red[tid >> 6] = mx;
    __syncthreads();
    if (tid == 0) {
        float m = red[0];
        for (int wv = 1; wv < 16; ++wv) m = fmaxf(m, red[wv]);
        sOffD = m + 1.0f;   // max_coord + 1
    }
    __syncthreads();
    const float offD = sOffD;

    // Phase 2: offset boxes (batched-NMS class trick), areas, per-thread alive mask
    float ox1[SLOTS], oy1[SLOTS], ox2[SLOTS], oy2[SLOTS], ar[SLOTS];
    uint32_t alive = 0u;
    #pragma unroll
    for (int k = 0; k < SLOTS; ++k) {
        float oi = (float)cls[k] * offD;
        ox1[k] = bx1[k] + oi; oy1[k] = by1[k] + oi;
        ox2[k] = bx2[k] + oi; oy2[k] = by2[k] + oi;
        ar[k] = (ox2[k] - ox1[k]) * (oy2[k] - oy1[k]);
        if (tid + k * 1024 < PRE) alive |= (1u << k);
    }

    // Phase 3: greedy picks. Pick = first active index (scores desc-sorted).
    int wstart = 0;
    for (int pick = 0; pick < POST; ++pick) {
        while (wstart < WPRE && actw[wstart] == 0u) ++wstart;   // uniform scan
        int i = (wstart < WPRE) ? (wstart * 32 + (__ffs(actw[wstart]) - 1)) : 0;

        // all threads recompute the pick's offset box (uniform, LDS/L1 broadcast)
        uint32_t fi = fidx[i];
        uint32_t qi = fi / NC;
        uint32_t ci = fi - qi * NC;
        float cx = pb[qi * 4 + 0], cy = pb[qi * 4 + 1], w = pb[qi * 4 + 2], h = pb[qi * 4 + 3];
        float pbx1 = (cx - 0.5f * w) * iw;
        float pby1 = (cy - 0.5f * h) * ih;
        float pbx2 = (cx + 0.5f * w) * iw;
        float pby2 = (cy + 0.5f * h) * ih;
        float oi = (float)ci * offD;
        float pox1 = pbx1 + oi, poy1 = pby1 + oi, pox2 = pbx2 + oi, poy2 = pby2 + oi;
        float pare = (pox2 - pox1) * (poy2 - poy1);

        if (tid == 0) {
            unsigned long long key = top[(size_t)img * PRE + i];
            uint32_t u = (uint32_t)(key >> 32);
            uint32_t b = (u & 0x80000000u) ? (u & 0x7FFFFFFFu) : ~u;
            float logit = __uint_as_float(b);
            out[img * POST + pick] = 1.0f / (1.0f + expf(-logit));
            out[BS * POST + img * POST + pick] = (float)ci;
            float* ob = out + 2 * BS * POST + ((size_t)img * POST + pick) * 4;
            ob[0] = pbx1; ob[1] = pby1; ob[2] = pbx2; ob[3] = pby2;
        }

        if (wstart < WPRE) {
            #pragma unroll
            for (int k = 0; k < SLOTS; ++k) {
                if (alive & (1u << k)) {
                    float xx1 = fmaxf(pox1, ox1[k]);
                    float yy1 = fmaxf(poy1, oy1[k]);
                    float xx2 = fminf(pox2, ox2[k]);
                    float yy2 = fminf(poy2, oy2[k]);
                    float inter = fmaxf(xx2 - xx1, 0.0f) * fmaxf(yy2 - yy1, 0.0f);
                    float uni = (pare + ar[k]) - inter;
                    float iou = inter / fmaxf(uni, 1e-9f);
                    if (!(iou <= 0.7f)) {        // pick suppresses itself too (iou=1)
                        alive &= ~(1u << k);
                        int r = tid + k * 1024;
                        atomicAnd(&actw[r >> 5], ~(1u << (r & 31)));
                    }
                }
            }
        }
        __syncthreads();   // clears visible before next pick's scan
    }
}

extern "C" void kernel_launch(void* const* d_in, const int* in_sizes, int n_in,
                              void* d_out, int out_size, void* d_ws, size_t ws_size,
                              hipStream_t stream) {
    const float* logits = (const float*)d_in[0];       // [128,900,91]
    const float* boxes  = (const float*)d_in[1];       // [128,900,4]
    const float* tsizes = (const float*)d_in[2];       // [128,2]
    float* out = (float*)d_out;                        // 76800 floats

    char* ws = (char*)d_ws;
    uint32_t* T   = (uint32_t*)(ws);                               // 128*4
    uint32_t* cnt = (uint32_t*)(ws + 1024);                        // 128*CNTS*4 = 8 KB
    unsigned long long* keys = (unsigned long long*)(ws + 16384);  // 128*16384*8 = 16 MB
    unsigned long long* top  = (unsigned long long*)(ws + 16384 + (size_t)BS * CAP * 8); // 128*10000*8

    k_thresh<<<BS, 1024, 0, stream>>>(logits, T, cnt);
    k_compact<<<dim3((NQC + 255) / 256, BS), 256, 0, stream>>>(logits, T, cnt, keys);
    k_sort<<<BS, 1024, 0, stream>>>(keys, cnt);
    k_merge<<<dim3(CAP / 256, BS), 256, 0, stream>>>(keys, top);
    k_nms<<<BS, 1024, 0, stream>>>(top, boxes, tsizes, out);
}

// Round 3
// 458.080 us; speedup vs baseline: 5.1777x; 1.1877x over previous
//
#include <hip/hip_runtime.h>
#include <cstdint>

#pragma clang fp contract(off)

#define BS   128
#define NQ   900
#define NC   91
#define NQC  (NQ * NC)   // 81900
#define PRE  10000
#define POST 100
#define CAP  16384
#define HALFN 8192
#define CNTS 16
#define TBITS 13
#define TBINS (1 << TBITS)
#define TSHIFT (32 - TBITS)
#define WPRE 320                  // ceil(PRE/32) words for active bitmask
#define NMS_T 512
#define SLOTS 20                  // 512 * 20 >= PRE
#define K_WIN 8

__device__ __forceinline__ uint32_t fkey(float f) {
    uint32_t b = __float_as_uint(f);
    return (b & 0x80000000u) ? ~b : (b | 0x80000000u);
}

// ---------------- Kernel A: per-image approximate threshold, single pass ----------------
__global__ void __launch_bounds__(1024) k_thresh(const float* __restrict__ logits,
                                                 uint32_t* __restrict__ T,
                                                 uint32_t* __restrict__ cnt) {
    int img = blockIdx.x;
    __shared__ uint32_t hist[TBINS];   // 32 KB
    __shared__ uint32_t part[1024];
    __shared__ uint32_t part2[32];
    __shared__ uint32_t sP, sTotal, sT;
    for (int i = threadIdx.x; i < TBINS; i += 1024) hist[i] = 0u;
    if (threadIdx.x == 0) cnt[img * CNTS] = 0u;
    __syncthreads();
    const float4* lg4 = (const float4*)(logits + (size_t)img * NQC);
    for (int i = threadIdx.x; i < NQC / 4; i += 1024) {
        float4 v = lg4[i];
        atomicAdd(&hist[fkey(v.x) >> TSHIFT], 1u);
        atomicAdd(&hist[fkey(v.y) >> TSHIFT], 1u);
        atomicAdd(&hist[fkey(v.z) >> TSHIFT], 1u);
        atomicAdd(&hist[fkey(v.w) >> TSHIFT], 1u);
    }
    __syncthreads();
    {
        uint32_t s = 0;
        int base = threadIdx.x * (TBINS / 1024);
        for (int j = 0; j < TBINS / 1024; ++j) s += hist[base + j];
        part[threadIdx.x] = s;
    }
    __syncthreads();
    if (threadIdx.x < 32) {
        uint32_t s2 = 0;
        for (int j = 0; j < 32; ++j) s2 += part[threadIdx.x * 32 + j];
        part2[threadIdx.x] = s2;
    }
    __syncthreads();
    if (threadIdx.x == 0) {
        uint32_t cum = 0;
        int w = 31;
        for (; w > 0; --w) { if (cum + part2[w] >= PRE) break; cum += part2[w]; }
        int t = w * 32 + 31;
        for (; t > w * 32; --t) { if (cum + part[t] >= PRE) break; cum += part[t]; }
        int b = t * (TBINS / 1024) + (TBINS / 1024 - 1);
        for (; b > t * (TBINS / 1024); --b) { if (cum + hist[b] >= PRE) break; cum += hist[b]; }
        sP = (uint32_t)b;
        sTotal = cum + hist[b];
        sT = ((uint32_t)b) << TSHIFT;
    }
    __syncthreads();
    if (sTotal > CAP) {   // fallback: refine 8 more bits within boundary bin
        uint32_t P = sP;
        for (int i = threadIdx.x; i < 256; i += 1024) part[i] = 0u;
        __syncthreads();
        for (int i = threadIdx.x; i < NQC / 4; i += 1024) {
            float4 v = lg4[i];
            uint32_t u;
            u = fkey(v.x); if ((u >> TSHIFT) == P) atomicAdd(&part[(u >> (TSHIFT - 8)) & 0xFFu], 1u);
            u = fkey(v.y); if ((u >> TSHIFT) == P) atomicAdd(&part[(u >> (TSHIFT - 8)) & 0xFFu], 1u);
            u = fkey(v.z); if ((u >> TSHIFT) == P) atomicAdd(&part[(u >> (TSHIFT - 8)) & 0xFFu], 1u);
            u = fkey(v.w); if ((u >> TSHIFT) == P) atomicAdd(&part[(u >> (TSHIFT - 8)) & 0xFFu], 1u);
        }
        __syncthreads();
        if (threadIdx.x == 0) {
            uint32_t countAbove = sTotal - hist[P];
            uint32_t K = PRE - countAbove;
            uint32_t cum = 0; int x = 255;
            for (; x > 0; --x) { if (cum + part[x] >= K) break; cum += part[x]; }
            sT = (P << TSHIFT) | (((uint32_t)x) << (TSHIFT - 8));
        }
        __syncthreads();
    }
    if (threadIdx.x == 0) T[img] = sT;
}

// ---------------- Kernel B: compact items with key >= T (aggregated atomics) ----------------
__global__ void k_compact(const float* __restrict__ logits, const uint32_t* __restrict__ T,
                          uint32_t* __restrict__ cnt, unsigned long long* __restrict__ keys) {
    __shared__ uint32_t sTot, sBase;
    int img = blockIdx.y;
    int i = blockIdx.x * blockDim.x + threadIdx.x;
    if (threadIdx.x == 0) sTot = 0u;
    __syncthreads();
    uint32_t u = 0u;
    bool pass = false;
    if (i < NQC) {
        u = fkey(logits[(size_t)img * NQC + i]);
        pass = (u >= T[img]);
    }
    unsigned long long mask = __ballot(pass);
    int lane = threadIdx.x & 63;
    uint32_t below = (uint32_t)__popcll(mask & ((1ull << lane) - 1ull));
    uint32_t wtot = (uint32_t)__popcll(mask);
    uint32_t wbase = 0u;
    if (lane == 0 && wtot) wbase = atomicAdd(&sTot, wtot);
    wbase = __shfl(wbase, 0, 64);
    __syncthreads();
    if (threadIdx.x == 0 && sTot) sBase = atomicAdd(&cnt[img * CNTS], sTot);
    __syncthreads();
    if (pass) {
        uint32_t pos = sBase + wbase + below;
        if (pos < CAP)
            keys[(size_t)img * CAP + pos] =
                ((unsigned long long)u << 32) | (unsigned long long)(0xFFFFFFFFu - (uint32_t)i);
    }
}

// ---------------- Kernel C: bitonic sort, one block per 8192-half (descending) ----------------
__global__ void __launch_bounds__(1024) k_sort(unsigned long long* __restrict__ keys,
                                               const uint32_t* __restrict__ cnt) {
    int img = blockIdx.y;
    int half = blockIdx.x;
    uint32_t n = cnt[img * CNTS]; if (n > CAP) n = CAP;
    __shared__ unsigned long long sh[HALFN];   // 64 KB
    unsigned long long* base = keys + (size_t)img * CAP;
    for (int i = threadIdx.x; i < HALFN; i += 1024) {
        int g = half * HALFN + i;
        sh[i] = (g < (int)n) ? base[g] : 0ull;
    }
    __syncthreads();
    for (int k = 2; k <= HALFN; k <<= 1) {
        for (int j = k >> 1; j > 0; j >>= 1) {
            for (int t = threadIdx.x; t < HALFN / 2; t += 1024) {
                int i = ((t & ~(j - 1)) << 1) | (t & (j - 1));
                int ixj = i | j;
                unsigned long long a = sh[i], b = sh[ixj];
                bool sw = ((i & k) == 0) ? (a < b) : (a > b);
                if (sw) { sh[i] = b; sh[ixj] = a; }
            }
            __syncthreads();
        }
    }
    for (int i = threadIdx.x; i < HALFN; i += 1024)
        base[half * HALFN + i] = sh[i];
}

// ---------------- Kernel D: merge-rank scatter of the two sorted halves -> top[PRE] ----------------
__global__ void k_merge(const unsigned long long* __restrict__ keys,
                        unsigned long long* __restrict__ top) {
    int img = blockIdx.y;
    int e = blockIdx.x * blockDim.x + threadIdx.x;  // [0, CAP)
    const unsigned long long* base = keys + (size_t)img * CAP;
    unsigned long long x = base[e];
    if (x == 0ull) return;  // padding
    int half = e >> 13;
    int pos = e & (HALFN - 1);
    const unsigned long long* other = base + (half ? 0 : HALFN);
    int lo = 0, hi = HALFN;
    while (lo < hi) {
        int mid = (lo + hi) >> 1;
        if (other[mid] > x) lo = mid + 1; else hi = mid;
    }
    int rank = pos + lo;
    if (rank < PRE) top[(size_t)img * PRE + rank] = x;
}

// ---------------- Kernel E: windowed greedy NMS ----------------
// Window-of-8 prefix-greedy acceptance == sequential greedy (proof: candidates are
// the first active indices in score order; next greedy pick is always the first
// candidate surviving all already-accepted ones). Cross-class pairs can never be
// suppressed: overhang into a neighbor class band is < w/2 => inter <= area/4 =>
// IoU < 1/3 < 0.7, so suppression only needs same-class IoU (bit-exact expressions).
__global__ void __launch_bounds__(NMS_T) k_nms(const unsigned long long* __restrict__ top,
                                               const float* __restrict__ pred_boxes,
                                               const float* __restrict__ target_sizes,
                                               float* __restrict__ out) {
    int img = blockIdx.x;
    __shared__ uint32_t fidx[PRE];     // 40 KB
    __shared__ uint32_t actw[WPRE];
    __shared__ float red[8];
    __shared__ float sOffD;
    __shared__ int   s_cand[K_WIN];
    __shared__ float s_cx1[K_WIN], s_cy1[K_WIN], s_cx2[K_WIN], s_cy2[K_WIN], s_car[K_WIN];
    __shared__ int   s_ccl[K_WIN];
    const int tid = threadIdx.x;
    const float ih = target_sizes[img * 2 + 0];
    const float iw = target_sizes[img * 2 + 1];
    const float* pb = pred_boxes + (size_t)img * NQ * 4;

    // Phase 1: load keys, raw scaled boxes, max coord
    float bx1[SLOTS], by1[SLOTS], bx2[SLOTS], by2[SLOTS];
    int cls[SLOTS];
    float mx = -INFINITY;
    #pragma unroll
    for (int k = 0; k < SLOTS; ++k) {
        int r = tid + k * NMS_T;
        bool v = (r < PRE);
        uint32_t f = 0u;
        if (v) {
            unsigned long long key = top[(size_t)img * PRE + r];
            f = ~(uint32_t)key;
            fidx[r] = f;
        }
        uint32_t q = v ? (f / NC) : 0u;
        cls[k] = (int)(f - q * NC);
        float cx = pb[q * 4 + 0], cy = pb[q * 4 + 1], w = pb[q * 4 + 2], h = pb[q * 4 + 3];
        float x1 = (cx - 0.5f * w) * iw;
        float y1 = (cy - 0.5f * h) * ih;
        float x2 = (cx + 0.5f * w) * iw;
        float y2 = (cy + 0.5f * h) * ih;
        bx1[k] = x1; by1[k] = y1; bx2[k] = x2; by2[k] = y2;
        if (v) mx = fmaxf(mx, fmaxf(fmaxf(x1, y1), fmaxf(x2, y2)));
    }
    for (int wI = tid; wI < WPRE; wI += NMS_T) {
        int base = wI * 32;
        uint32_t m = 0xFFFFFFFFu;
        if (base + 32 > PRE) m = (base >= PRE) ? 0u : (0xFFFFFFFFu >> (base + 32 - PRE));
        actw[wI] = m;
    }
    for (int off = 32; off > 0; off >>= 1) mx = fmaxf(mx, __shfl_down(mx, off, 64));
    if ((tid & 63) == 0) red[tid >> 6] = mx;
    __syncthreads();
    if (tid == 0) {
        float m = red[0];
        for (int wv = 1; wv < NMS_T / 64; ++wv) m = fmaxf(m, red[wv]);
        sOffD = m + 1.0f;   // max_coord + 1
    }
    __syncthreads();
    const float offD = sOffD;

    // Phase 2: offset boxes + areas, per-thread alive mask
    float ox1[SLOTS], oy1[SLOTS], ox2[SLOTS], oy2[SLOTS], ar[SLOTS];
    uint32_t alive = 0u;
    #pragma unroll
    for (int k = 0; k < SLOTS; ++k) {
        float oi = (float)cls[k] * offD;
        ox1[k] = bx1[k] + oi; oy1[k] = by1[k] + oi;
        ox2[k] = bx2[k] + oi; oy2[k] = by2[k] + oi;
        ar[k] = (ox2[k] - ox1[k]) * (oy2[k] - oy1[k]);
        if (tid + k * NMS_T < PRE) alive |= (1u << k);
    }
    __syncthreads();

    // Phase 3: windowed greedy picks
    int wstart = 0;
    int pick = 0;
    while (pick < POST) {
        while (wstart < WPRE && actw[wstart] == 0u) ++wstart;   // uniform
        if (wstart >= WPRE) {
            // all suppressed: reference argmax over all -inf = index 0 forever
            uint32_t fi = fidx[0];
            uint32_t qi = fi / NC;
            uint32_t ci = fi - qi * NC;
            float cx = pb[qi * 4 + 0], cy = pb[qi * 4 + 1], w = pb[qi * 4 + 2], h = pb[qi * 4 + 3];
            float rx1 = (cx - 0.5f * w) * iw;
            float ry1 = (cy - 0.5f * h) * ih;
            float rx2 = (cx + 0.5f * w) * iw;
            float ry2 = (cy + 0.5f * h) * ih;
            unsigned long long key = top[(size_t)img * PRE + 0];
            uint32_t u = (uint32_t)(key >> 32);
            uint32_t b = (u & 0x80000000u) ? (u & 0x7FFFFFFFu) : ~u;
            float score = 1.0f / (1.0f + expf(-__uint_as_float(b)));
            for (int p = pick + tid; p < POST; p += NMS_T) {
                out[img * POST + p] = score;
                out[BS * POST + img * POST + p] = (float)ci;
                float* ob = out + 2 * BS * POST + ((size_t)img * POST + p) * 4;
                ob[0] = rx1; ob[1] = ry1; ob[2] = rx2; ob[3] = ry2;
            }
            break;
        }

        // uniform scan: first up to K_WIN active indices
        int ncand = 0;
        int myr = -1;
        {
            int wI = wstart;
            uint32_t wbits = actw[wI];
            #pragma unroll
            for (int j = 0; j < K_WIN; ++j) {
                while (wbits == 0u && wI + 1 < WPRE) { ++wI; wbits = actw[wI]; }
                if (wbits) {
                    int r = wI * 32 + (__ffs(wbits) - 1);
                    wbits &= wbits - 1u;
                    if (tid == 0) s_cand[j] = r;
                    if (tid == j) myr = r;
                    ++ncand;
                }
            }
        }

        // threads 0..ncand-1 compute their candidate's offset box into LDS
        if (tid < ncand) {
            uint32_t fi = fidx[myr];
            uint32_t q = fi / NC;
            int c = (int)(fi - q * NC);
            float cx = pb[q * 4 + 0], cy = pb[q * 4 + 1], w = pb[q * 4 + 2], h = pb[q * 4 + 3];
            float x1 = (cx - 0.5f * w) * iw;
            float y1 = (cy - 0.5f * h) * ih;
            float x2 = (cx + 0.5f * w) * iw;
            float y2 = (cy + 0.5f * h) * ih;
            float o = (float)c * offD;
            float a1 = x1 + o, b1 = y1 + o, a2 = x2 + o, b2 = y2 + o;
            s_cx1[tid] = a1; s_cy1[tid] = b1; s_cx2[tid] = a2; s_cy2[tid] = b2;
            s_car[tid] = (a2 - a1) * (b2 - b1);
            s_ccl[tid] = c;
        }
        __syncthreads();

        // all threads: load candidates to registers (static indexing)
        float cx1[K_WIN], cy1[K_WIN], cx2[K_WIN], cy2[K_WIN], car_[K_WIN];
        int ccl[K_WIN];
        #pragma unroll
        for (int j = 0; j < K_WIN; ++j) {
            bool v = (j < ncand);
            cx1[j] = v ? s_cx1[j] : 0.0f;
            cy1[j] = v ? s_cy1[j] : 0.0f;
            cx2[j] = v ? s_cx2[j] : 0.0f;
            cy2[j] = v ? s_cy2[j] : 0.0f;
            car_[j] = v ? s_car[j] : 0.0f;
            ccl[j] = v ? s_ccl[j] : -1;
        }

        // uniform prefix-greedy acceptance within the window (full offset IoU)
        uint32_t accMask = 0u;
        int A = 0;
        const int maxA = POST - pick;
        #pragma unroll
        for (int j = 0; j < K_WIN; ++j) {
            if (j < ncand && A < maxA) {
                bool ok = true;
                #pragma unroll
                for (int m = 0; m < K_WIN; ++m) {
                    if (m < j && ((accMask >> m) & 1u)) {
                        float xx1 = fmaxf(cx1[m], cx1[j]);
                        float yy1 = fmaxf(cy1[m], cy1[j]);
                        float xx2 = fminf(cx2[m], cx2[j]);
                        float yy2 = fminf(cy2[m], cy2[j]);
                        float inter = fmaxf(xx2 - xx1, 0.0f) * fmaxf(yy2 - yy1, 0.0f);
                        float uni = (car_[m] + car_[j]) - inter;
                        float iou = inter / fmaxf(uni, 1e-9f);
                        if (!(iou <= 0.7f)) ok = false;
                    }
                }
                if (ok) { accMask |= (1u << j); ++A; }
            }
        }

        // outputs: thread ord writes accepted candidate j (pick order = candidate order)
        #pragma unroll
        for (int j = 0; j < K_WIN; ++j) {
            if ((accMask >> j) & 1u) {
                int ord = __popc(accMask & ((1u << j) - 1u));
                if (tid == ord) {
                    int r = s_cand[j];
                    uint32_t fi = fidx[r];
                    uint32_t qi = fi / NC;
                    uint32_t ci = fi - qi * NC;
                    float cx = pb[qi * 4 + 0], cy = pb[qi * 4 + 1], w = pb[qi * 4 + 2], h = pb[qi * 4 + 3];
                    float rx1 = (cx - 0.5f * w) * iw;
                    float ry1 = (cy - 0.5f * h) * ih;
                    float rx2 = (cx + 0.5f * w) * iw;
                    float ry2 = (cy + 0.5f * h) * ih;
                    unsigned long long key = top[(size_t)img * PRE + r];
                    uint32_t u = (uint32_t)(key >> 32);
                    uint32_t b = (u & 0x80000000u) ? (u & 0x7FFFFFFFu) : ~u;
                    float score = 1.0f / (1.0f + expf(-__uint_as_float(b)));
                    int p = pick + ord;
                    out[img * POST + p] = score;
                    out[BS * POST + img * POST + p] = (float)ci;
                    float* ob = out + 2 * BS * POST + ((size_t)img * POST + p) * 4;
                    ob[0] = rx1; ob[1] = ry1; ob[2] = rx2; ob[3] = ry2;
                }
            }
        }

        // suppression: same-class only (cross-class IoU < 1/3 < 0.7 provably)
        #pragma unroll
        for (int k = 0; k < SLOTS; ++k) {
            if ((alive >> k) & 1u) {
                bool dead = false;
                #pragma unroll
                for (int j = 0; j < K_WIN; ++j) {
                    if (((accMask >> j) & 1u) && cls[k] == ccl[j]) {
                        float xx1 = fmaxf(cx1[j], ox1[k]);
                        float yy1 = fmaxf(cy1[j], oy1[k]);
                        float xx2 = fminf(cx2[j], ox2[k]);
                        float yy2 = fminf(cy2[j], oy2[k]);
                        float inter = fmaxf(xx2 - xx1, 0.0f) * fmaxf(yy2 - yy1, 0.0f);
                        float uni = (car_[j] + ar[k]) - inter;
                        float iou = inter / fmaxf(uni, 1e-9f);
                        if (!(iou <= 0.7f)) dead = true;
                    }
                }
                if (dead) {
                    alive &= ~(1u << k);
                    int r = tid + k * NMS_T;
                    atomicAnd(&actw[r >> 5], ~(1u << (r & 31)));
                }
            }
        }
        pick += A;
        __syncthreads();
    }
}

extern "C" void kernel_launch(void* const* d_in, const int* in_sizes, int n_in,
                              void* d_out, int out_size, void* d_ws, size_t ws_size,
                              hipStream_t stream) {
    const float* logits = (const float*)d_in[0];
    const float* boxes  = (const float*)d_in[1];
    const float* tsizes = (const float*)d_in[2];
    float* out = (float*)d_out;

    char* ws = (char*)d_ws;
    uint32_t* T   = (uint32_t*)(ws);
    uint32_t* cnt = (uint32_t*)(ws + 1024);
    unsigned long long* keys = (unsigned long long*)(ws + 16384);
    unsigned long long* top  = (unsigned long long*)(ws + 16384 + (size_t)BS * CAP * 8);

    k_thresh<<<BS, 1024, 0, stream>>>(logits, T, cnt);
    k_compact<<<dim3((NQC + 255) / 256, BS), 256, 0, stream>>>(logits, T, cnt, keys);
    k_sort<<<dim3(2, BS), 1024, 0, stream>>>(keys, cnt);
    k_merge<<<dim3(CAP / 256, BS), 256, 0, stream>>>(keys, top);
    k_nms<<<BS, 512, 0, stream>>>(top, boxes, tsizes, out);
}

// Round 5
// 342.913 us; speedup vs baseline: 6.9167x; 1.3358x over previous
//
#include <hip/hip_runtime.h>
#include <cstdint>

#pragma clang fp contract(off)

#define BS   128
#define NQ   900
#define NC   91
#define NQC  (NQ * NC)   // 81900
#define PRE  10000
#define POST 100
#define SEGA 8192
#define SEGB 4096        // R4 had 2048: B-count = 1808 + ~2 bin widths (~128 each) overflowed -> poisoned top tail -> OOB fault
#define KSTRIDE (SEGA + SEGB)     // 12288 keys per image
#define CNTS 16
#define TBITS 13
#define TBINS (1 << TBITS)
#define TSHIFT (32 - TBITS)
#define WPRE 320                  // ceil(PRE/32) words for active bitmask
#define K_WIN 8

typedef unsigned long long ull;

__device__ __forceinline__ uint32_t fkey(float f) {
    uint32_t b = __float_as_uint(f);
    return (b & 0x80000000u) ? ~b : (b | 0x80000000u);
}

// defensive: q<NQ always holds for valid keys (f<NQC); clamp turns any capacity bug
// into wrong-value (caught by harness) instead of an HSA memory fault.
__device__ __forceinline__ uint32_t qclamp(uint32_t q) { return (q < NQ) ? q : (NQ - 1); }

// ============ Kernel 1: fused threshold + two-way compaction (one block per image) ============
// T_lo: largest bin boundary with suffix-count >= PRE  (so M = cntA+cntB >= PRE)
// T_hi: smallest bin boundary with suffix-count <= SEGA (so cntA <= 8192)
// Segment A: key >= T_hi.  Segment B: T_lo <= key < T_hi (~1850 items typ., <= SEGB;
// 8-bit refine fallback if not). All A-keys > all B-keys => sorted concat == sorted merge.
__global__ void __launch_bounds__(1024) k_select(const float* __restrict__ logits,
                                                 uint32_t* __restrict__ cnt,
                                                 ull* __restrict__ keys) {
    int img = blockIdx.x;
    const int tid = threadIdx.x;
    __shared__ uint32_t hist[TBINS];   // 32 KB
    __shared__ uint32_t part[1024];
    __shared__ uint32_t part2[32];
    __shared__ uint32_t sTlo, sThi, sBlo, sCumAboveLo, sM, sM1;
    __shared__ uint32_t ctrA, ctrB;

    for (int i = tid; i < TBINS; i += 1024) hist[i] = 0u;
    if (tid == 0) { ctrA = 0u; ctrB = 0u; }
    __syncthreads();

    const float* lg = logits + (size_t)img * NQC;
    const float4* lg4 = (const float4*)lg;
    for (int i = tid; i < NQC / 4; i += 1024) {
        float4 v = lg4[i];
        atomicAdd(&hist[fkey(v.x) >> TSHIFT], 1u);
        atomicAdd(&hist[fkey(v.y) >> TSHIFT], 1u);
        atomicAdd(&hist[fkey(v.z) >> TSHIFT], 1u);
        atomicAdd(&hist[fkey(v.w) >> TSHIFT], 1u);
    }
    __syncthreads();
    {
        uint32_t s = 0;
        int base = tid * (TBINS / 1024);
        for (int j = 0; j < TBINS / 1024; ++j) s += hist[base + j];
        part[tid] = s;
    }
    __syncthreads();
    if (tid < 32) {
        uint32_t s2 = 0;
        for (int j = 0; j < 32; ++j) s2 += part[tid * 32 + j];
        part2[tid] = s2;
    }
    __syncthreads();
    if (tid == 0) {
        // --- search b_lo: suffix >= PRE ---
        uint32_t cum = 0; int w = 31;
        for (; w > 0; --w) { if (cum + part2[w] >= PRE) break; cum += part2[w]; }
        int t = w * 32 + 31;
        for (; t > w * 32; --t) { if (cum + part[t] >= PRE) break; cum += part[t]; }
        int b = t * (TBINS / 1024) + (TBINS / 1024 - 1);
        for (; b > t * (TBINS / 1024); --b) { if (cum + hist[b] >= PRE) break; cum += hist[b]; }
        sBlo = (uint32_t)b;
        sCumAboveLo = cum;
        sM = cum + hist[b];
        sTlo = ((uint32_t)b) << TSHIFT;
        // --- search b_hi: largest suffix <= SEGA ---
        uint32_t cum2 = 0; int w2 = 31;
        for (; w2 >= 0; --w2) { if (cum2 + part2[w2] > SEGA) break; cum2 += part2[w2]; }
        int t2 = w2 * 32 + 31;
        for (; t2 >= w2 * 32; --t2) { if (cum2 + part[t2] > SEGA) break; cum2 += part[t2]; }
        int b2 = t2 * (TBINS / 1024) + (TBINS / 1024 - 1);
        for (; b2 >= t2 * (TBINS / 1024); --b2) { if (cum2 + hist[b2] > SEGA) break; cum2 += hist[b2]; }
        sM1 = cum2;
        sThi = (b2 >= TBINS - 1) ? 0xFFFFFFFFu : (((uint32_t)(b2 + 1)) << TSHIFT);
    }
    __syncthreads();

    if (sM - sM1 > SEGB) {   // fallback: refine Tlo by 8 bits within its boundary bin
        uint32_t P = sBlo;
        for (int i = tid; i < 256; i += 1024) part[i] = 0u;
        __syncthreads();
        for (int i = tid; i < NQC / 4; i += 1024) {
            float4 v = lg4[i];
            uint32_t u;
            u = fkey(v.x); if ((u >> TSHIFT) == P) atomicAdd(&part[(u >> (TSHIFT - 8)) & 0xFFu], 1u);
            u = fkey(v.y); if ((u >> TSHIFT) == P) atomicAdd(&part[(u >> (TSHIFT - 8)) & 0xFFu], 1u);
            u = fkey(v.z); if ((u >> TSHIFT) == P) atomicAdd(&part[(u >> (TSHIFT - 8)) & 0xFFu], 1u);
            u = fkey(v.w); if ((u >> TSHIFT) == P) atomicAdd(&part[(u >> (TSHIFT - 8)) & 0xFFu], 1u);
        }
        __syncthreads();
        if (tid == 0) {
            uint32_t K = PRE - sCumAboveLo;
            uint32_t cum = 0; int x = 255;
            for (; x > 0; --x) { if (cum + part[x] >= K) break; cum += part[x]; }
            sTlo = (P << TSHIFT) | (((uint32_t)x) << (TSHIFT - 8));
        }
        __syncthreads();
    }

    const uint32_t Tlo = sTlo, Thi = sThi;
    ull* kA = keys + (size_t)img * KSTRIDE;
    ull* kB = kA + SEGA;
    const int lane = tid & 63;
    for (int base = 0; base < NQC; base += 1024) {
        int i = base + tid;
        uint32_t u = 0u;
        bool inb = (i < NQC);
        if (inb) u = fkey(lg[i]);
        bool a = inb && (u >= Thi);
        bool bb = inb && !a && (u >= Tlo);
        ull ma = __ballot(a), mb = __ballot(bb);
        uint32_t belowA = (uint32_t)__popcll(ma & ((1ull << lane) - 1ull));
        uint32_t belowB = (uint32_t)__popcll(mb & ((1ull << lane) - 1ull));
        uint32_t baseA = 0u, baseB = 0u;
        if (lane == 0) {
            if (ma) baseA = atomicAdd(&ctrA, (uint32_t)__popcll(ma));
            if (mb) baseB = atomicAdd(&ctrB, (uint32_t)__popcll(mb));
        }
        baseA = __shfl(baseA, 0, 64);
        baseB = __shfl(baseB, 0, 64);
        ull kv = ((ull)u << 32) | (ull)(0xFFFFFFFFu - (uint32_t)i);
        if (a)  { uint32_t p = baseA + belowA; if (p < SEGA) kA[p] = kv; }
        if (bb) { uint32_t p = baseB + belowB; if (p < SEGB) kB[p] = kv; }
    }
    __syncthreads();
    if (tid == 0) {
        cnt[img * CNTS + 0] = (ctrA < SEGA) ? ctrA : SEGA;
        cnt[img * CNTS + 1] = (ctrB < SEGB) ? ctrB : SEGB;
    }
}

// ============ Kernel 2: bitonic sort per segment (desc), write concatenated into top ============
__global__ void __launch_bounds__(1024) k_sortseg(ull* __restrict__ keys,
                                                  const uint32_t* __restrict__ cnt,
                                                  ull* __restrict__ top) {
    int img = blockIdx.y;
    int seg = blockIdx.x;
    const int tid = threadIdx.x;
    uint32_t cntA = cnt[img * CNTS + 0];
    uint32_t n = seg ? cnt[img * CNTS + 1] : cntA;
    const int SIZE = seg ? SEGB : SEGA;
    ull* base = keys + (size_t)img * KSTRIDE + (seg ? SEGA : 0);
    __shared__ ull sh[SEGA];   // 64 KB
    for (int i = tid; i < SIZE; i += 1024) sh[i] = (i < (int)n) ? base[i] : 0ull;
    __syncthreads();
    for (int k = 2; k <= SIZE; k <<= 1) {
        for (int j = k >> 1; j > 0; j >>= 1) {
            for (int t = tid; t < SIZE / 2; t += 1024) {
                int i = ((t & ~(j - 1)) << 1) | (t & (j - 1));
                int ixj = i | j;
                ull a = sh[i], b = sh[ixj];
                bool sw = ((i & k) == 0) ? (a < b) : (a > b);
                if (sw) { sh[i] = b; sh[ixj] = a; }
            }
            __syncthreads();
        }
    }
    ull* dst = top + (size_t)img * PRE;
    if (seg == 0) {
        int lim = ((int)n < PRE) ? (int)n : PRE;
        for (int i = tid; i < lim; i += 1024) dst[i] = sh[i];
    } else {
        int need = PRE - (int)cntA;
        if (need > SIZE) need = SIZE;
        for (int i = tid; i < need; i += 1024) dst[cntA + i] = sh[i];
    }
}

// ============ Kernel 3: windowed greedy NMS with class buckets ============
// Cross-class suppression provably impossible (offset bands: inter <= area/4 => IoU <= 1/3
// < 0.7), so suppression scans only the accepted candidate's class bucket (~110 items).
// Item boxes recomputed from pred_boxes (L1-hot) with the exact reference fp chain.
__global__ void __launch_bounds__(1024) k_nms(const ull* __restrict__ top,
                                              const float* __restrict__ pred_boxes,
                                              const float* __restrict__ target_sizes,
                                              float* __restrict__ out) {
    int img = blockIdx.x;
    const int tid = threadIdx.x;
    __shared__ uint32_t fidx[PRE];          // 40000 B
    __shared__ unsigned short clist[PRE];   // 20000 B
    __shared__ uint32_t actw[WPRE];
    __shared__ uint32_t ccnt[NC];
    __shared__ uint32_t cstart[NC + 1];
    __shared__ uint32_t cfill[NC];
    __shared__ float red[16];
    __shared__ float sOffD;
    __shared__ int   s_cand[K_WIN];
    __shared__ float s_cx1[K_WIN], s_cy1[K_WIN], s_cx2[K_WIN], s_cy2[K_WIN], s_car[K_WIN];
    __shared__ int   s_ccl[K_WIN], s_cbs[K_WIN], s_cbe[K_WIN];

    const float ih = target_sizes[img * 2 + 0];
    const float iw = target_sizes[img * 2 + 1];
    const float* pb = pred_boxes + (size_t)img * NQ * 4;
    const ull* tp = top + (size_t)img * PRE;

    for (int c = tid; c < NC; c += 1024) ccnt[c] = 0u;
    for (int wI = tid; wI < WPRE; wI += 1024) {
        int base = wI * 32;
        uint32_t m = 0xFFFFFFFFu;
        if (base + 32 > PRE) m = (base >= PRE) ? 0u : (0xFFFFFFFFu >> (base + 32 - PRE));
        actw[wI] = m;
    }
    __syncthreads();

    // Phase 1: keys -> fidx, class histogram, max scaled coord
    float mx = -INFINITY;
    #pragma unroll
    for (int k = 0; k < 10; ++k) {
        int r = tid + k * 1024;
        if (r < PRE) {
            ull key = tp[r];
            uint32_t f = ~(uint32_t)key;
            fidx[r] = f;
            uint32_t q = qclamp(f / NC);
            uint32_t c = f - (f / NC) * NC;
            atomicAdd(&ccnt[c % NC], 1u);
            float cx = pb[q * 4 + 0], cy = pb[q * 4 + 1], w = pb[q * 4 + 2], h = pb[q * 4 + 3];
            float x1 = (cx - 0.5f * w) * iw;
            float y1 = (cy - 0.5f * h) * ih;
            float x2 = (cx + 0.5f * w) * iw;
            float y2 = (cy + 0.5f * h) * ih;
            mx = fmaxf(mx, fmaxf(fmaxf(x1, y1), fmaxf(x2, y2)));
        }
    }
    for (int off = 32; off > 0; off >>= 1) mx = fmaxf(mx, __shfl_down(mx, off, 64));
    if ((tid & 63) == 0) red[tid >> 6] = mx;
    __syncthreads();
    if (tid == 0) {
        float m = red[0];
        for (int wv = 1; wv < 16; ++wv) m = fmaxf(m, red[wv]);
        sOffD = m + 1.0f;   // max_coord + 1
        uint32_t run = 0;
        for (int c = 0; c < NC; ++c) { cstart[c] = run; cfill[c] = run; run += ccnt[c]; }
        cstart[NC] = run;
    }
    __syncthreads();
    const float offD = sOffD;

    // bucket scatter (order within bucket irrelevant)
    #pragma unroll
    for (int k = 0; k < 10; ++k) {
        int r = tid + k * 1024;
        if (r < PRE) {
            uint32_t c = fidx[r] % NC;
            uint32_t pos = atomicAdd(&cfill[c], 1u);
            if (pos < PRE) clist[pos] = (unsigned short)r;
        }
    }
    __syncthreads();

    // Phase 3: windowed greedy picks
    int wstart = 0;
    int pick = 0;
    while (pick < POST) {
        while (wstart < WPRE && actw[wstart] == 0u) ++wstart;   // uniform
        if (wstart >= WPRE) {
            // all suppressed: reference argmax over all -inf = index 0 forever
            uint32_t fi = fidx[0];
            uint32_t qi = qclamp(fi / NC);
            uint32_t ci = fi - (fi / NC) * NC;
            float cx = pb[qi * 4 + 0], cy = pb[qi * 4 + 1], w = pb[qi * 4 + 2], h = pb[qi * 4 + 3];
            float rx1 = (cx - 0.5f * w) * iw;
            float ry1 = (cy - 0.5f * h) * ih;
            float rx2 = (cx + 0.5f * w) * iw;
            float ry2 = (cy + 0.5f * h) * ih;
            ull key = tp[0];
            uint32_t u = (uint32_t)(key >> 32);
            uint32_t b = (u & 0x80000000u) ? (u & 0x7FFFFFFFu) : ~u;
            float score = 1.0f / (1.0f + expf(-__uint_as_float(b)));
            for (int p = pick + tid; p < POST; p += 1024) {
                out[img * POST + p] = score;
                out[BS * POST + img * POST + p] = (float)ci;
                float* ob = out + 2 * BS * POST + ((size_t)img * POST + p) * 4;
                ob[0] = rx1; ob[1] = ry1; ob[2] = rx2; ob[3] = ry2;
            }
            break;
        }

        // uniform scan: first up to K_WIN active indices (score order)
        int ncand = 0;
        int myr = -1;
        {
            int wI = wstart;
            uint32_t wbits = actw[wI];
            #pragma unroll
            for (int j = 0; j < K_WIN; ++j) {
                while (wbits == 0u && wI + 1 < WPRE) { ++wI; wbits = actw[wI]; }
                if (wbits) {
                    int r = wI * 32 + (__ffs(wbits) - 1);
                    wbits &= wbits - 1u;
                    if (tid == 0) s_cand[j] = r;
                    if (tid == j) myr = r;
                    ++ncand;
                }
            }
        }

        if (tid < ncand) {
            uint32_t fi = fidx[myr];
            uint32_t q = qclamp(fi / NC);
            int c = (int)(fi - (fi / NC) * NC);
            float cx = pb[q * 4 + 0], cy = pb[q * 4 + 1], w = pb[q * 4 + 2], h = pb[q * 4 + 3];
            float x1 = (cx - 0.5f * w) * iw;
            float y1 = (cy - 0.5f * h) * ih;
            float x2 = (cx + 0.5f * w) * iw;
            float y2 = (cy + 0.5f * h) * ih;
            float o = (float)c * offD;
            float a1 = x1 + o, b1 = y1 + o, a2 = x2 + o, b2 = y2 + o;
            s_cx1[tid] = a1; s_cy1[tid] = b1; s_cx2[tid] = a2; s_cy2[tid] = b2;
            s_car[tid] = (a2 - a1) * (b2 - b1);
            s_ccl[tid] = c;
            s_cbs[tid] = (int)cstart[(c >= 0 && c < NC) ? c : 0];
            s_cbe[tid] = (int)cstart[((c >= 0 && c < NC) ? c : 0) + 1];
        }
        __syncthreads();

        float cx1[K_WIN], cy1[K_WIN], cx2[K_WIN], cy2[K_WIN], car_[K_WIN];
        #pragma unroll
        for (int j = 0; j < K_WIN; ++j) {
            bool v = (j < ncand);
            cx1[j] = v ? s_cx1[j] : 0.0f;
            cy1[j] = v ? s_cy1[j] : 0.0f;
            cx2[j] = v ? s_cx2[j] : 0.0f;
            cy2[j] = v ? s_cy2[j] : 0.0f;
            car_[j] = v ? s_car[j] : 0.0f;
        }

        // uniform prefix-greedy acceptance within the window (full offset IoU)
        uint32_t accMask = 0u;
        int A = 0;
        const int maxA = POST - pick;
        #pragma unroll
        for (int j = 0; j < K_WIN; ++j) {
            if (j < ncand && A < maxA) {
                bool ok = true;
                #pragma unroll
                for (int m = 0; m < K_WIN; ++m) {
                    if (m < j && ((accMask >> m) & 1u)) {
                        float xx1 = fmaxf(cx1[m], cx1[j]);
                        float yy1 = fmaxf(cy1[m], cy1[j]);
                        float xx2 = fminf(cx2[m], cx2[j]);
                        float yy2 = fminf(cy2[m], cy2[j]);
                        float inter = fmaxf(xx2 - xx1, 0.0f) * fmaxf(yy2 - yy1, 0.0f);
                        float uni = (car_[m] + car_[j]) - inter;
                        float iou = inter / fmaxf(uni, 1e-9f);
                        if (!(iou <= 0.7f)) ok = false;
                    }
                }
                if (ok) { accMask |= (1u << j); ++A; }
            }
        }

        // outputs (pick order = candidate order among accepted)
        #pragma unroll
        for (int j = 0; j < K_WIN; ++j) {
            if ((accMask >> j) & 1u) {
                int ord = __popc(accMask & ((1u << j) - 1u));
                if (tid == ord) {
                    int r = s_cand[j];
                    uint32_t fi = fidx[r];
                    uint32_t qi = qclamp(fi / NC);
                    uint32_t ci = fi - (fi / NC) * NC;
                    float cx = pb[qi * 4 + 0], cy = pb[qi * 4 + 1], w = pb[qi * 4 + 2], h = pb[qi * 4 + 3];
                    float rx1 = (cx - 0.5f * w) * iw;
                    float ry1 = (cy - 0.5f * h) * ih;
                    float rx2 = (cx + 0.5f * w) * iw;
                    float ry2 = (cy + 0.5f * h) * ih;
                    ull key = tp[r];
                    uint32_t u = (uint32_t)(key >> 32);
                    uint32_t b = (u & 0x80000000u) ? (u & 0x7FFFFFFFu) : ~u;
                    float score = 1.0f / (1.0f + expf(-__uint_as_float(b)));
                    int p = pick + ord;
                    out[img * POST + p] = score;
                    out[BS * POST + img * POST + p] = (float)ci;
                    float* ob = out + 2 * BS * POST + ((size_t)img * POST + p) * 4;
                    ob[0] = rx1; ob[1] = ry1; ob[2] = rx2; ob[3] = ry2;
                }
            }
        }

        // suppression: only the accepted candidates' class buckets
        #pragma unroll
        for (int j = 0; j < K_WIN; ++j) {
            if ((accMask >> j) & 1u) {
                int bs = s_cbs[j], be = s_cbe[j];
                float o = (float)s_ccl[j] * offD;
                for (int t2 = bs + tid; t2 < be; t2 += 1024) {
                    int r2 = clist[t2];
                    if (actw[r2 >> 5] & (1u << (r2 & 31))) {
                        uint32_t f2 = fidx[r2];
                        uint32_t q2 = qclamp(f2 / NC);
                        float cx = pb[q2 * 4 + 0], cy = pb[q2 * 4 + 1], w = pb[q2 * 4 + 2], h = pb[q2 * 4 + 3];
                        float jx1 = (cx - 0.5f * w) * iw + o;
                        float jy1 = (cy - 0.5f * h) * ih + o;
                        float jx2 = (cx + 0.5f * w) * iw + o;
                        float jy2 = (cy + 0.5f * h) * ih + o;
                        float arj = (jx2 - jx1) * (jy2 - jy1);
                        float xx1 = fmaxf(cx1[j], jx1);
                        float yy1 = fmaxf(cy1[j], jy1);
                        float xx2 = fminf(cx2[j], jx2);
                        float yy2 = fminf(cy2[j], jy2);
                        float inter = fmaxf(xx2 - xx1, 0.0f) * fmaxf(yy2 - yy1, 0.0f);
                        float uni = (car_[j] + arj) - inter;
                        float iou = inter / fmaxf(uni, 1e-9f);
                        if (!(iou <= 0.7f)) atomicAnd(&actw[r2 >> 5], ~(1u << (r2 & 31)));
                    }
                }
            }
        }
        pick += A;
        __syncthreads();
    }
}

extern "C" void kernel_launch(void* const* d_in, const int* in_sizes, int n_in,
                              void* d_out, int out_size, void* d_ws, size_t ws_size,
                              hipStream_t stream) {
    const float* logits = (const float*)d_in[0];
    const float* boxes  = (const float*)d_in[1];
    const float* tsizes = (const float*)d_in[2];
    float* out = (float*)d_out;

    char* ws = (char*)d_ws;
    uint32_t* cnt = (uint32_t*)(ws);                                  // 128*16*4 = 8 KB
    ull* keys = (ull*)(ws + 16384);                                   // 128*12288*8 = 12.6 MB
    ull* top  = (ull*)(ws + 16384 + (size_t)BS * KSTRIDE * 8);        // 128*10000*8 = 10.24 MB

    k_select<<<BS, 1024, 0, stream>>>(logits, cnt, keys);
    k_sortseg<<<dim3(2, BS), 1024, 0, stream>>>(keys, cnt, top);
    k_nms<<<BS, 1024, 0, stream>>>(top, boxes, tsizes, out);
}